// Round 1
// baseline (5473.722 us; speedup 1.0000x reference)
//
#include <hip/hip_runtime.h>
#include <math.h>

// ---------------------------------------------------------------------------
// SNN generator pipeline, fp32 correctness-first baseline.
// Workspace layout (floats unless noted):
//   lin   (8,8192)                 65536 f
//   I     (8,128,16,16)            262144 f      (constant LIF input)
//   spk   u8 [200][1024][18*18]    66,355,200 B  (zero-padded spike planes)
//   y1p   [25][8][128][256]        6,553,600 f   (conv1 partials over t-chunks)
//   y1    (8,128,16,16)            262144 f
//   x2p   (8,128,34,34)            1,183,744 f   (padded post-BN2 upsampled)
//   y2    (8,64,32,32)             524288 f
//   y2n   (8,64,34,34)             591,872 f     (padded post-BN3)
// total ~99.3 MiB
// ---------------------------------------------------------------------------

__global__ __launch_bounds__(256) void k_linear(
    const float* __restrict__ z, const float* __restrict__ w,
    const float* __restrict__ bias, float* __restrict__ out) {
  int g = blockIdx.x * 256 + threadIdx.x;   // 65536 = (b, j)
  int b = g >> 13, j = g & 8191;
  float acc = bias[j];
  const float* zp = z + b * 100;
  for (int l = 0; l < 100; ++l) acc += zp[l] * w[l * 8192 + j];
  out[g] = acc;
}

// BN1 (training stats over (N,H,W)=512, eps 1e-5) + nearest upsample 2x -> I
__global__ __launch_bounds__(256) void k_bn1_up(
    const float* __restrict__ lin, const float* __restrict__ g1,
    const float* __restrict__ be1, float* __restrict__ I) {
  int ch = blockIdx.x, tid = threadIdx.x;
  __shared__ float red[256];
  int n0 = tid, n1 = tid + 256;                       // n = b*64 + hw
  float v0 = lin[(n0 >> 6) * 8192 + ch * 64 + (n0 & 63)];
  float v1 = lin[(n1 >> 6) * 8192 + ch * 64 + (n1 & 63)];
  red[tid] = v0 + v1; __syncthreads();
  for (int s = 128; s > 0; s >>= 1) { if (tid < s) red[tid] += red[tid + s]; __syncthreads(); }
  float mean = red[0] * (1.0f / 512.0f);
  __syncthreads();
  float d0 = v0 - mean, d1 = v1 - mean;
  red[tid] = d0 * d0 + d1 * d1; __syncthreads();
  for (int s = 128; s > 0; s >>= 1) { if (tid < s) red[tid] += red[tid + s]; __syncthreads(); }
  float var = red[0] * (1.0f / 512.0f);
  float coef = g1[ch] / sqrtf(var + 1e-5f);
  float beta = be1[ch];
  float q0 = (v0 - mean) * coef + beta;
  float q1 = (v1 - mean) * coef + beta;
#pragma unroll
  for (int k = 0; k < 2; ++k) {
    int n = k ? n1 : n0; float q = k ? q1 : q0;
    int b = n >> 6, hw = n & 63, h = hw >> 3, w = hw & 7;
    float* o = I + (size_t)(b * 128 + ch) * 256 + (2 * h) * 16 + 2 * w;
    o[0] = q; o[1] = q; o[16] = q; o[17] = q;
  }
}

// LIF: mem0=0; reset=(mem>1) BEFORE update; mem=0.95*mem+I-reset; spk=(mem>1).
// Writes u8 spikes into zero-padded 18x18 planes (halo pre-zeroed by memset).
__global__ __launch_bounds__(256) void k_lif(
    const float* __restrict__ I, unsigned char* __restrict__ spk) {
  int g = blockIdx.x * 256 + threadIdx.x;   // (b2, ch, h, w)
  float in = I[g];
  int plane = g >> 8;                        // b2*128 + ch, 0..1023
  int hw = g & 255, h = hw >> 4, w = hw & 15;
  size_t off = (size_t)(h + 1) * 18 + (w + 1);
  float mem = 0.0f;
  for (int t = 0; t < 200; ++t) {
    float reset = (mem > 1.0f) ? 1.0f : 0.0f;
    mem = 0.95f * mem + in - reset;
    spk[(size_t)(t * 1024 + plane) * 324 + off] = (mem > 1.0f) ? (unsigned char)1 : (unsigned char)0;
  }
}

// conv1 partial: block=(t,octile,b). K-chunk = 1024 (b2,ch) x 9 taps.
// thread = pixel, 16 oc accumulators; weights are block-uniform -> s_load.
__global__ __launch_bounds__(256) void k_conv1(
    const unsigned char* __restrict__ spk, const float* __restrict__ wc1,
    float* __restrict__ y1p) {
  int t = blockIdx.x;        // 0..24 (local time within this output batch)
  int octile = blockIdx.y;   // 0..7  (16 oc each)
  int b = blockIdx.z;        // 0..7
  int tid = threadIdx.x;
  int h = tid >> 4, w = tid & 15;
  int T = b * 25 + t;        // global time step
  const unsigned char* sp = spk + (size_t)(T * 1024) * 324 + h * 18 + w;
  float acc[16];
#pragma unroll
  for (int i = 0; i < 16; ++i) acc[i] = 0.0f;
  // w_c1[oc][c][ki][kj], c = t*1024 + q
  const float* wbase = wc1 + ((size_t)(octile * 16) * 25600 + (size_t)t * 1024) * 9;
  for (int q = 0; q < 1024; ++q) {
    const unsigned char* p = sp + (size_t)q * 324;
    float s0 = p[0],  s1 = p[1],  s2 = p[2];
    float s3 = p[18], s4 = p[19], s5 = p[20];
    float s6 = p[36], s7 = p[37], s8 = p[38];
    const float* wq = wbase + (size_t)q * 9;
#pragma unroll
    for (int ol = 0; ol < 16; ++ol) {
      const float* wp = wq + (size_t)ol * 25600 * 9;
      acc[ol] += s0 * wp[0] + s1 * wp[1] + s2 * wp[2]
               + s3 * wp[3] + s4 * wp[4] + s5 * wp[5]
               + s6 * wp[6] + s7 * wp[7] + s8 * wp[8];
    }
  }
  float* out = y1p + ((size_t)((t * 8 + b) * 128 + octile * 16)) * 256 + tid;
#pragma unroll
  for (int ol = 0; ol < 16; ++ol) out[(size_t)ol * 256] = acc[ol];
}

// reduce 25 t-partials + conv1 bias -> y1 (b,oc,16,16)
__global__ __launch_bounds__(256) void k_reduce1(
    const float* __restrict__ y1p, const float* __restrict__ bc1,
    float* __restrict__ y1) {
  int g = blockIdx.x * 256 + threadIdx.x;  // (b, oc, px)
  int b = g >> 15, oc = (g >> 8) & 127, px = g & 255;
  float acc = bc1[oc];
  for (int t = 0; t < 25; ++t)
    acc += y1p[(size_t)((t * 8 + b) * 128 + oc) * 256 + px];
  y1[g] = acc;
}

// BN2 (eps 0.8, stats over 2048) + leaky(0.2) + upsample2x into padded x2p
__global__ __launch_bounds__(256) void k_bn2_up(
    const float* __restrict__ y1, const float* __restrict__ g2,
    const float* __restrict__ be2, float* __restrict__ x2p) {
  int ch = blockIdx.x, tid = threadIdx.x;
  __shared__ float red[256];
  float v[8]; float s = 0.0f;
#pragma unroll
  for (int k = 0; k < 8; ++k) {
    int n = tid + k * 256;  // n = b*256 + px
    v[k] = y1[(size_t)((n >> 8) * 128 + ch) * 256 + (n & 255)];
    s += v[k];
  }
  red[tid] = s; __syncthreads();
  for (int st = 128; st > 0; st >>= 1) { if (tid < st) red[tid] += red[tid + st]; __syncthreads(); }
  float mean = red[0] * (1.0f / 2048.0f);
  __syncthreads();
  s = 0.0f;
#pragma unroll
  for (int k = 0; k < 8; ++k) { float d = v[k] - mean; s += d * d; }
  red[tid] = s; __syncthreads();
  for (int st = 128; st > 0; st >>= 1) { if (tid < st) red[tid] += red[tid + st]; __syncthreads(); }
  float var = red[0] * (1.0f / 2048.0f);
  float coef = g2[ch] / sqrtf(var + 0.8f);
  float beta = be2[ch];
#pragma unroll
  for (int k = 0; k < 8; ++k) {
    int n = tid + k * 256;
    int b = n >> 8, px = n & 255, h = px >> 4, w = px & 15;
    float q = (v[k] - mean) * coef + beta;
    q = (q >= 0.0f) ? q : 0.2f * q;
    float* o = x2p + (size_t)(b * 128 + ch) * 1156 + (2 * h + 1) * 34 + (2 * w + 1);
    o[0] = q; o[1] = q; o[34] = q; o[35] = q;
  }
}

// conv2: block=(octile 0..15, b), thread = 4 pixels x 4 oc
__global__ __launch_bounds__(256) void k_conv2(
    const float* __restrict__ x2p, const float* __restrict__ wc2,
    const float* __restrict__ bc2, float* __restrict__ y2) {
  int octile = blockIdx.x, b = blockIdx.y, tid = threadIdx.x;
  float acc[16];
#pragma unroll
  for (int i = 0; i < 16; ++i) acc[i] = 0.0f;
  const float* base = x2p + (size_t)(b * 128) * 1156;
  for (int ch = 0; ch < 128; ++ch) {
    const float* pl = base + (size_t)ch * 1156;
    float sv[4][9];
#pragma unroll
    for (int j = 0; j < 4; ++j) {
      int p = tid + j * 256, h = p >> 5, w = p & 31;
      const float* pp = pl + h * 34 + w;
      sv[j][0] = pp[0];  sv[j][1] = pp[1];  sv[j][2] = pp[2];
      sv[j][3] = pp[34]; sv[j][4] = pp[35]; sv[j][5] = pp[36];
      sv[j][6] = pp[68]; sv[j][7] = pp[69]; sv[j][8] = pp[70];
    }
#pragma unroll
    for (int ol = 0; ol < 4; ++ol) {
      const float* wp = wc2 + (size_t)((octile * 4 + ol) * 128 + ch) * 9;
#pragma unroll
      for (int j = 0; j < 4; ++j) {
        acc[ol * 4 + j] += sv[j][0] * wp[0] + sv[j][1] * wp[1] + sv[j][2] * wp[2]
                         + sv[j][3] * wp[3] + sv[j][4] * wp[4] + sv[j][5] * wp[5]
                         + sv[j][6] * wp[6] + sv[j][7] * wp[7] + sv[j][8] * wp[8];
      }
    }
  }
#pragma unroll
  for (int ol = 0; ol < 4; ++ol) {
    int oc = octile * 4 + ol;
    float bias = bc2[oc];
#pragma unroll
    for (int j = 0; j < 4; ++j)
      y2[(size_t)(b * 64 + oc) * 1024 + tid + j * 256] = acc[ol * 4 + j] + bias;
  }
}

// BN3 (eps 0.8, stats over 8192) + leaky -> padded y2n
__global__ __launch_bounds__(256) void k_bn3(
    const float* __restrict__ y2, const float* __restrict__ g3,
    const float* __restrict__ be3, float* __restrict__ y2n) {
  int ch = blockIdx.x, tid = threadIdx.x;
  __shared__ float red[256];
  float v[32]; float s = 0.0f;
#pragma unroll
  for (int k = 0; k < 32; ++k) {
    int n = tid + k * 256;  // n = b*1024 + px
    v[k] = y2[(size_t)((n >> 10) * 64 + ch) * 1024 + (n & 1023)];
    s += v[k];
  }
  red[tid] = s; __syncthreads();
  for (int st = 128; st > 0; st >>= 1) { if (tid < st) red[tid] += red[tid + st]; __syncthreads(); }
  float mean = red[0] * (1.0f / 8192.0f);
  __syncthreads();
  s = 0.0f;
#pragma unroll
  for (int k = 0; k < 32; ++k) { float d = v[k] - mean; s += d * d; }
  red[tid] = s; __syncthreads();
  for (int st = 128; st > 0; st >>= 1) { if (tid < st) red[tid] += red[tid + st]; __syncthreads(); }
  float var = red[0] * (1.0f / 8192.0f);
  float coef = g3[ch] / sqrtf(var + 0.8f);
  float beta = be3[ch];
#pragma unroll
  for (int k = 0; k < 32; ++k) {
    int n = tid + k * 256;
    int b = n >> 10, px = n & 1023, h = px >> 5, w = px & 31;
    float q = (v[k] - mean) * coef + beta;
    q = (q >= 0.0f) ? q : 0.2f * q;
    y2n[(size_t)(b * 64 + ch) * 1156 + (h + 1) * 34 + (w + 1)] = q;
  }
}

// conv3 (3 oc) + bias + tanh -> d_out (8,3,32,32)
__global__ __launch_bounds__(256) void k_conv3(
    const float* __restrict__ y2n, const float* __restrict__ wc3,
    const float* __restrict__ bc3, float* __restrict__ out) {
  int quarter = blockIdx.x & 3, b = blockIdx.x >> 2;
  int p = quarter * 256 + threadIdx.x, h = p >> 5, w = p & 31;
  float a0 = 0.0f, a1 = 0.0f, a2 = 0.0f;
  const float* base = y2n + (size_t)(b * 64) * 1156 + h * 34 + w;
  for (int ch = 0; ch < 64; ++ch) {
    const float* pp = base + (size_t)ch * 1156;
    float s0 = pp[0],  s1 = pp[1],  s2 = pp[2];
    float s3 = pp[34], s4 = pp[35], s5 = pp[36];
    float s6 = pp[68], s7 = pp[69], s8 = pp[70];
    const float* w0 = wc3 + (size_t)ch * 9;
    const float* w1 = wc3 + (size_t)(64 + ch) * 9;
    const float* w2 = wc3 + (size_t)(128 + ch) * 9;
    a0 += s0*w0[0]+s1*w0[1]+s2*w0[2]+s3*w0[3]+s4*w0[4]+s5*w0[5]+s6*w0[6]+s7*w0[7]+s8*w0[8];
    a1 += s0*w1[0]+s1*w1[1]+s2*w1[2]+s3*w1[3]+s4*w1[4]+s5*w1[5]+s6*w1[6]+s7*w1[7]+s8*w1[8];
    a2 += s0*w2[0]+s1*w2[1]+s2*w2[2]+s3*w2[3]+s4*w2[4]+s5*w2[5]+s6*w2[6]+s7*w2[7]+s8*w2[8];
  }
  out[(size_t)(b * 3 + 0) * 1024 + p] = tanhf(a0 + bc3[0]);
  out[(size_t)(b * 3 + 1) * 1024 + p] = tanhf(a1 + bc3[1]);
  out[(size_t)(b * 3 + 2) * 1024 + p] = tanhf(a2 + bc3[2]);
}

extern "C" void kernel_launch(void* const* d_in, const int* in_sizes, int n_in,
                              void* d_out, int out_size, void* d_ws, size_t ws_size,
                              hipStream_t stream) {
  const float* z    = (const float*)d_in[0];
  const float* w_l1 = (const float*)d_in[1];
  const float* b_l1 = (const float*)d_in[2];
  const float* g1   = (const float*)d_in[3];
  const float* be1  = (const float*)d_in[4];
  const float* w_c1 = (const float*)d_in[5];
  const float* b_c1 = (const float*)d_in[6];
  const float* g2   = (const float*)d_in[7];
  const float* be2  = (const float*)d_in[8];
  const float* w_c2 = (const float*)d_in[9];
  const float* b_c2 = (const float*)d_in[10];
  const float* g3   = (const float*)d_in[11];
  const float* be3  = (const float*)d_in[12];
  const float* w_c3 = (const float*)d_in[13];
  const float* b_c3 = (const float*)d_in[14];
  float* out = (float*)d_out;

  char* ws = (char*)d_ws;
  float* lin = (float*)ws;                                  // 65536
  float* I   = lin + 65536;                                 // 262144
  unsigned char* spk = (unsigned char*)(I + 262144);
  size_t spk_bytes = (size_t)200 * 1024 * 324;              // 66,355,200
  float* y1p = (float*)(spk + spk_bytes);                   // 6,553,600
  float* y1  = y1p + 6553600;                               // 262144
  float* x2p = y1 + 262144;                                 // 1,183,744
  float* y2  = x2p + 1183744;                               // 524288
  float* y2n = y2 + 524288;                                 // 591,872

  hipMemsetAsync(spk, 0, spk_bytes, stream);
  hipMemsetAsync(x2p, 0, (size_t)1183744 * 4, stream);
  hipMemsetAsync(y2n, 0, (size_t)591872 * 4, stream);

  k_linear <<<256, 256, 0, stream>>>(z, w_l1, b_l1, lin);
  k_bn1_up <<<128, 256, 0, stream>>>(lin, g1, be1, I);
  k_lif    <<<1024, 256, 0, stream>>>(I, spk);
  k_conv1  <<<dim3(25, 8, 8), 256, 0, stream>>>(spk, w_c1, y1p);
  k_reduce1<<<1024, 256, 0, stream>>>(y1p, b_c1, y1);
  k_bn2_up <<<128, 256, 0, stream>>>(y1, g2, be2, x2p);
  k_conv2  <<<dim3(16, 8), 256, 0, stream>>>(x2p, w_c2, b_c2, y2);
  k_bn3    <<<64, 256, 0, stream>>>(y2, g3, be3, y2n);
  k_conv3  <<<32, 256, 0, stream>>>(y2n, w_c3, b_c3, out);
}

// Round 3
// 843.775 us; speedup vs baseline: 6.4872x; 6.4872x over previous
//
#include <hip/hip_runtime.h>
#include <math.h>

// ---------------------------------------------------------------------------
// SNN generator pipeline. Round 2: fix round-1 workspace overflow (y1p was
// 4x under-allocated and conv1 trampled spkTb while reading it).
// conv1 partials now atomicAdd directly into y1 (no y1p, no k_reduce1).
//
// Workspace (peak ~69.6 MB), with lifetime aliasing:
//   phase A (through conv1):
//     wT    f16 [9][128][25600]   at 0          58,982,400 B
//     spkTb u8  [324][25600]      at 58,982,400  8,294,400 B
//     lin   f32 (8,8192)          at 67,276,800    262,144 B
//     I     f32 (8,128,16,16)     at 67,538,944  1,048,576 B
//     y1    f32 (8,128,16,16)     at 68,587,520  1,048,576 B
//   phase B (after conv1; aliases the dead wT region):
//     x2p   f32 (8,128,34,34)     at 0           4,734,976 B
//     y2n   f32 (8,64,34,34)      at 4,734,976   2,367,488 B
//     y2    f32 (8,64,32,32)      at 7,102,464   2,097,152 B
// ---------------------------------------------------------------------------

typedef _Float16 half8 __attribute__((ext_vector_type(8)));
typedef float f32x4 __attribute__((ext_vector_type(4)));
typedef unsigned int uint4v __attribute__((ext_vector_type(4)));

union F16Frag { uint4v u4; unsigned int u[4]; half8 h; };

__global__ __launch_bounds__(256) void k_linear(
    const float* __restrict__ z, const float* __restrict__ w,
    const float* __restrict__ bias, float* __restrict__ out) {
  int g = blockIdx.x * 256 + threadIdx.x;   // 65536 = (b, j)
  int b = g >> 13, j = g & 8191;
  float acc = bias[j];
  const float* zp = z + b * 100;
  for (int l = 0; l < 100; ++l) acc += zp[l] * w[l * 8192 + j];
  out[g] = acc;
}

// BN1 (stats over 512, eps 1e-5) + nearest upsample 2x -> I (8,128,16,16)
__global__ __launch_bounds__(256) void k_bn1_up(
    const float* __restrict__ lin, const float* __restrict__ g1,
    const float* __restrict__ be1, float* __restrict__ I) {
  int ch = blockIdx.x, tid = threadIdx.x;
  __shared__ float red[256];
  int n0 = tid, n1 = tid + 256;                       // n = b*64 + hw
  float v0 = lin[(n0 >> 6) * 8192 + ch * 64 + (n0 & 63)];
  float v1 = lin[(n1 >> 6) * 8192 + ch * 64 + (n1 & 63)];
  red[tid] = v0 + v1; __syncthreads();
  for (int s = 128; s > 0; s >>= 1) { if (tid < s) red[tid] += red[tid + s]; __syncthreads(); }
  float mean = red[0] * (1.0f / 512.0f);
  __syncthreads();
  float d0 = v0 - mean, d1 = v1 - mean;
  red[tid] = d0 * d0 + d1 * d1; __syncthreads();
  for (int s = 128; s > 0; s >>= 1) { if (tid < s) red[tid] += red[tid + s]; __syncthreads(); }
  float var = red[0] * (1.0f / 512.0f);
  float coef = g1[ch] / sqrtf(var + 1e-5f);
  float beta = be1[ch];
  float q0 = (v0 - mean) * coef + beta;
  float q1 = (v1 - mean) * coef + beta;
#pragma unroll
  for (int k = 0; k < 2; ++k) {
    int n = k ? n1 : n0; float q = k ? q1 : q0;
    int b = n >> 6, hw = n & 63, h = hw >> 3, w = hw & 7;
    float* o = I + (size_t)(b * 128 + ch) * 256 + (2 * h) * 16 + 2 * w;
    o[0] = q; o[1] = q; o[16] = q; o[17] = q;
  }
}

// LIF with bit-packed transposed spike output.
// thread g: px = g>>10, plane = g&1023. Wave = 64 consecutive planes, same px.
// spkTb[pos][col/8] bit (col&7), col = t*1024 + plane. Halo pre-zeroed.
__global__ __launch_bounds__(256) void k_lif(
    const float* __restrict__ I, unsigned char* __restrict__ spkTb) {
  int g = blockIdx.x * 256 + threadIdx.x;
  int px = g >> 10, plane = g & 1023;
  int lane = threadIdx.x & 63;
  float in = I[plane * 256 + px];
  int pos = ((px >> 4) + 1) * 18 + (px & 15) + 1;
  unsigned long long* wsrow =
      (unsigned long long*)(spkTb + (size_t)pos * 25600 + ((plane - lane) >> 3));
  float mem = 0.0f;
  for (int t = 0; t < 200; ++t) {
    float reset = (mem > 1.0f) ? 1.0f : 0.0f;
    mem = 0.95f * mem + in - reset;
    unsigned long long m = __ballot(mem > 1.0f);
    if (lane == 0) wsrow[t * 16] = m;   // t*128 bytes
  }
}

// One-time weight transform: w_c1 (128,25600,3,3) fp32 -> wT[tap][oc][c] f16
__global__ __launch_bounds__(256) void k_wtrans(
    const float* __restrict__ wc1, _Float16* __restrict__ wT) {
  size_t g = (size_t)blockIdx.x * 256 + threadIdx.x;  // oc*25600 + c
  int oc = (int)(g / 25600);
  int c  = (int)(g - (size_t)oc * 25600);
  const float* src = wc1 + g * 9;
#pragma unroll
  for (int tap = 0; tap < 9; ++tap)
    wT[(size_t)(tap * 128 + oc) * 25600 + c] = (_Float16)src[tap];
}

__device__ inline void expand8(unsigned int v, F16Frag& f) {
  // bit j -> f16 element j (0x3C00 = 1.0h)
  f.u[0] = ((v & 1u) * 0x3C00u)        | (((v >> 1) & 1u) * 0x3C000000u);
  f.u[1] = (((v >> 2) & 1u) * 0x3C00u) | (((v >> 3) & 1u) * 0x3C000000u);
  f.u[2] = (((v >> 4) & 1u) * 0x3C00u) | (((v >> 5) & 1u) * 0x3C000000u);
  f.u[3] = (((v >> 6) & 1u) * 0x3C00u) | (((v >> 7) & 1u) * 0x3C000000u);
}

// conv1 implicit GEMM. Block = (part = tl*2+kq, b). M=128 oc, N=256 px,
// K-chunk = 512 channels x 9 taps. Wave w handles spatial rows h = 4w..4w+3.
// MFMA 16x16x32 f16: A[m=lane&15][k=quad*8+j], B[k=quad*8+j][n=lane&15],
// D: col=lane&15, row=quad*4+reg.  Partials atomicAdd into y1 (zero-init).
__global__ __launch_bounds__(256, 2) void k_conv1_mfma(
    const unsigned char* __restrict__ spkTb, const _Float16* __restrict__ wT,
    float* __restrict__ y1) {
  int part = blockIdx.x;            // 0..49 = tl*2 + kq
  int b    = blockIdx.y;            // 0..7
  int tl = part >> 1, kq = part & 1;
  int wave = threadIdx.x >> 6, lane = threadIdx.x & 63;
  int quad = lane >> 4, l16 = lane & 15;
  int T = b * 25 + tl;
  int cbase = tl * 1024 + kq * 512;            // A channel base
  int colbyte = T * 128 + kq * 64 + quad;      // B column-byte base

  f32x4 acc[8][4] = {};             // [mt][nt]
  const int h0 = wave * 4;

  for (int tap = 0; tap < 9; ++tap) {
    int dh = tap / 3, dw = tap - dh * 3;
    const unsigned char* bbase =
        spkTb + (size_t)((h0 + dh) * 18 + l16 + dw) * 25600 + colbyte;
    const _Float16* abase =
        wT + (size_t)(tap * 128 + l16) * 25600 + cbase + quad * 8;
    for (int ks = 0; ks < 16; ++ks) {
      F16Frag afr[8];
#pragma unroll
      for (int mt = 0; mt < 8; ++mt)
        afr[mt].u4 = *(const uint4v*)(abase + (size_t)mt * 16 * 25600 + ks * 32);
      F16Frag bfr[4];
#pragma unroll
      for (int nt = 0; nt < 4; ++nt) {
        unsigned int v = bbase[(size_t)nt * 18 * 25600 + ks * 4];
        expand8(v, bfr[nt]);
      }
#pragma unroll
      for (int mt = 0; mt < 8; ++mt)
#pragma unroll
        for (int nt = 0; nt < 4; ++nt)
          acc[mt][nt] = __builtin_amdgcn_mfma_f32_16x16x32_f16(
              afr[mt].h, bfr[nt].h, acc[mt][nt], 0, 0, 0);
    }
  }
  float* ybase = y1 + (size_t)b * 128 * 256;
#pragma unroll
  for (int mt = 0; mt < 8; ++mt)
#pragma unroll
    for (int nt = 0; nt < 4; ++nt) {
      int h = h0 + nt;
#pragma unroll
      for (int r = 0; r < 4; ++r) {
        int oc = mt * 16 + quad * 4 + r;
        atomicAdd(&ybase[(size_t)oc * 256 + h * 16 + l16], acc[mt][nt][r]);
      }
    }
}

// BN2 (eps 0.8, stats over 2048) + conv1 bias + leaky(0.2) + upsample2x
// into padded x2p
__global__ __launch_bounds__(256) void k_bn2_up(
    const float* __restrict__ y1, const float* __restrict__ bc1,
    const float* __restrict__ g2, const float* __restrict__ be2,
    float* __restrict__ x2p) {
  int ch = blockIdx.x, tid = threadIdx.x;
  __shared__ float red[256];
  float bias = bc1[ch];
  float v[8]; float s = 0.0f;
#pragma unroll
  for (int k = 0; k < 8; ++k) {
    int n = tid + k * 256;  // n = b*256 + px
    v[k] = y1[(size_t)((n >> 8) * 128 + ch) * 256 + (n & 255)] + bias;
    s += v[k];
  }
  red[tid] = s; __syncthreads();
  for (int st = 128; st > 0; st >>= 1) { if (tid < st) red[tid] += red[tid + st]; __syncthreads(); }
  float mean = red[0] * (1.0f / 2048.0f);
  __syncthreads();
  s = 0.0f;
#pragma unroll
  for (int k = 0; k < 8; ++k) { float d = v[k] - mean; s += d * d; }
  red[tid] = s; __syncthreads();
  for (int st = 128; st > 0; st >>= 1) { if (tid < st) red[tid] += red[tid + st]; __syncthreads(); }
  float var = red[0] * (1.0f / 2048.0f);
  float coef = g2[ch] / sqrtf(var + 0.8f);
  float beta = be2[ch];
#pragma unroll
  for (int k = 0; k < 8; ++k) {
    int n = tid + k * 256;
    int b = n >> 8, px = n & 255, h = px >> 4, w = px & 15;
    float q = (v[k] - mean) * coef + beta;
    q = (q >= 0.0f) ? q : 0.2f * q;
    float* o = x2p + (size_t)(b * 128 + ch) * 1156 + (2 * h + 1) * 34 + (2 * w + 1);
    o[0] = q; o[1] = q; o[34] = q; o[35] = q;
  }
}

// conv2: block=(octile 0..15, b), thread = 4 pixels x 4 oc
__global__ __launch_bounds__(256) void k_conv2(
    const float* __restrict__ x2p, const float* __restrict__ wc2,
    const float* __restrict__ bc2, float* __restrict__ y2) {
  int octile = blockIdx.x, b = blockIdx.y, tid = threadIdx.x;
  float acc[16];
#pragma unroll
  for (int i = 0; i < 16; ++i) acc[i] = 0.0f;
  const float* base = x2p + (size_t)(b * 128) * 1156;
  for (int ch = 0; ch < 128; ++ch) {
    const float* pl = base + (size_t)ch * 1156;
    float sv[4][9];
#pragma unroll
    for (int j = 0; j < 4; ++j) {
      int p = tid + j * 256, h = p >> 5, w = p & 31;
      const float* pp = pl + h * 34 + w;
      sv[j][0] = pp[0];  sv[j][1] = pp[1];  sv[j][2] = pp[2];
      sv[j][3] = pp[34]; sv[j][4] = pp[35]; sv[j][5] = pp[36];
      sv[j][6] = pp[68]; sv[j][7] = pp[69]; sv[j][8] = pp[70];
    }
#pragma unroll
    for (int ol = 0; ol < 4; ++ol) {
      const float* wp = wc2 + (size_t)((octile * 4 + ol) * 128 + ch) * 9;
#pragma unroll
      for (int j = 0; j < 4; ++j) {
        acc[ol * 4 + j] += sv[j][0] * wp[0] + sv[j][1] * wp[1] + sv[j][2] * wp[2]
                         + sv[j][3] * wp[3] + sv[j][4] * wp[4] + sv[j][5] * wp[5]
                         + sv[j][6] * wp[6] + sv[j][7] * wp[7] + sv[j][8] * wp[8];
      }
    }
  }
#pragma unroll
  for (int ol = 0; ol < 4; ++ol) {
    int oc = octile * 4 + ol;
    float bias = bc2[oc];
#pragma unroll
    for (int j = 0; j < 4; ++j)
      y2[(size_t)(b * 64 + oc) * 1024 + tid + j * 256] = acc[ol * 4 + j] + bias;
  }
}

// BN3 (eps 0.8, stats over 8192) + leaky -> padded y2n
__global__ __launch_bounds__(256) void k_bn3(
    const float* __restrict__ y2, const float* __restrict__ g3,
    const float* __restrict__ be3, float* __restrict__ y2n) {
  int ch = blockIdx.x, tid = threadIdx.x;
  __shared__ float red[256];
  float v[32]; float s = 0.0f;
#pragma unroll
  for (int k = 0; k < 32; ++k) {
    int n = tid + k * 256;  // n = b*1024 + px
    v[k] = y2[(size_t)((n >> 10) * 64 + ch) * 1024 + (n & 1023)];
    s += v[k];
  }
  red[tid] = s; __syncthreads();
  for (int st = 128; st > 0; st >>= 1) { if (tid < st) red[tid] += red[tid + st]; __syncthreads(); }
  float mean = red[0] * (1.0f / 8192.0f);
  __syncthreads();
  s = 0.0f;
#pragma unroll
  for (int k = 0; k < 32; ++k) { float d = v[k] - mean; s += d * d; }
  red[tid] = s; __syncthreads();
  for (int st = 128; st > 0; st >>= 1) { if (tid < st) red[tid] += red[tid + st]; __syncthreads(); }
  float var = red[0] * (1.0f / 8192.0f);
  float coef = g3[ch] / sqrtf(var + 0.8f);
  float beta = be3[ch];
#pragma unroll
  for (int k = 0; k < 32; ++k) {
    int n = tid + k * 256;
    int b = n >> 10, px = n & 1023, h = px >> 5, w = px & 31;
    float q = (v[k] - mean) * coef + beta;
    q = (q >= 0.0f) ? q : 0.2f * q;
    y2n[(size_t)(b * 64 + ch) * 1156 + (h + 1) * 34 + (w + 1)] = q;
  }
}

// conv3 (3 oc) + bias + tanh -> d_out (8,3,32,32)
__global__ __launch_bounds__(256) void k_conv3(
    const float* __restrict__ y2n, const float* __restrict__ wc3,
    const float* __restrict__ bc3, float* __restrict__ out) {
  int quarter = blockIdx.x & 3, b = blockIdx.x >> 2;
  int p = quarter * 256 + threadIdx.x, h = p >> 5, w = p & 31;
  float a0 = 0.0f, a1 = 0.0f, a2 = 0.0f;
  const float* base = y2n + (size_t)(b * 64) * 1156 + h * 34 + w;
  for (int ch = 0; ch < 64; ++ch) {
    const float* pp = base + (size_t)ch * 1156;
    float s0 = pp[0],  s1 = pp[1],  s2 = pp[2];
    float s3 = pp[34], s4 = pp[35], s5 = pp[36];
    float s6 = pp[68], s7 = pp[69], s8 = pp[70];
    const float* w0 = wc3 + (size_t)ch * 9;
    const float* w1 = wc3 + (size_t)(64 + ch) * 9;
    const float* w2 = wc3 + (size_t)(128 + ch) * 9;
    a0 += s0*w0[0]+s1*w0[1]+s2*w0[2]+s3*w0[3]+s4*w0[4]+s5*w0[5]+s6*w0[6]+s7*w0[7]+s8*w0[8];
    a1 += s0*w1[0]+s1*w1[1]+s2*w1[2]+s3*w1[3]+s4*w1[4]+s5*w1[5]+s6*w1[6]+s7*w1[7]+s8*w1[8];
    a2 += s0*w2[0]+s1*w2[1]+s2*w2[2]+s3*w2[3]+s4*w2[4]+s5*w2[5]+s6*w2[6]+s7*w2[7]+s8*w2[8];
  }
  out[(size_t)(b * 3 + 0) * 1024 + p] = tanhf(a0 + bc3[0]);
  out[(size_t)(b * 3 + 1) * 1024 + p] = tanhf(a1 + bc3[1]);
  out[(size_t)(b * 3 + 2) * 1024 + p] = tanhf(a2 + bc3[2]);
}

extern "C" void kernel_launch(void* const* d_in, const int* in_sizes, int n_in,
                              void* d_out, int out_size, void* d_ws, size_t ws_size,
                              hipStream_t stream) {
  const float* z    = (const float*)d_in[0];
  const float* w_l1 = (const float*)d_in[1];
  const float* b_l1 = (const float*)d_in[2];
  const float* g1   = (const float*)d_in[3];
  const float* be1  = (const float*)d_in[4];
  const float* w_c1 = (const float*)d_in[5];
  const float* b_c1 = (const float*)d_in[6];
  const float* g2   = (const float*)d_in[7];
  const float* be2  = (const float*)d_in[8];
  const float* w_c2 = (const float*)d_in[9];
  const float* b_c2 = (const float*)d_in[10];
  const float* g3   = (const float*)d_in[11];
  const float* be3  = (const float*)d_in[12];
  const float* w_c3 = (const float*)d_in[13];
  const float* b_c3 = (const float*)d_in[14];
  float* out = (float*)d_out;

  char* ws = (char*)d_ws;
  // phase A
  _Float16* wT = (_Float16*)ws;                             // 58,982,400 B
  unsigned char* spkTb = (unsigned char*)(ws + 58982400);   //  8,294,400 B
  float* lin = (float*)(ws + 67276800);                     //    262,144 B
  float* I   = (float*)(ws + 67538944);                     //  1,048,576 B
  float* y1  = (float*)(ws + 68587520);                     //  1,048,576 B
  // phase B (aliases wT region; written only after conv1 completes)
  float* x2p = (float*)ws;                                  //  4,734,976 B
  float* y2n = (float*)(ws + 4734976);                      //  2,367,488 B
  float* y2  = (float*)(ws + 7102464);                      //  2,097,152 B

  size_t spkTb_bytes = (size_t)324 * 25600;

  hipMemsetAsync(spkTb, 0, spkTb_bytes, stream);
  hipMemsetAsync(y1, 0, (size_t)262144 * 4, stream);

  k_wtrans <<<12800, 256, 0, stream>>>(w_c1, wT);
  k_linear <<<256, 256, 0, stream>>>(z, w_l1, b_l1, lin);
  k_bn1_up <<<128, 256, 0, stream>>>(lin, g1, be1, I);
  k_lif    <<<1024, 256, 0, stream>>>(I, spkTb);
  k_conv1_mfma<<<dim3(50, 8), 256, 0, stream>>>(spkTb, wT, y1);

  // phase B setup (must be after conv1: x2p/y2n alias the wT region)
  hipMemsetAsync(x2p, 0, (size_t)1183744 * 4, stream);
  hipMemsetAsync(y2n, 0, (size_t)591872 * 4, stream);

  k_bn2_up <<<128, 256, 0, stream>>>(y1, b_c1, g2, be2, x2p);
  k_conv2  <<<dim3(16, 8), 256, 0, stream>>>(x2p, w_c2, b_c2, y2);
  k_bn3    <<<64, 256, 0, stream>>>(y2, g3, be3, y2n);
  k_conv3  <<<32, 256, 0, stream>>>(y2n, w_c3, b_c3, out);
}

// Round 4
// 771.539 us; speedup vs baseline: 7.0946x; 1.0936x over previous
//
#include <hip/hip_runtime.h>
#include <math.h>

// ---------------------------------------------------------------------------
// SNN generator. Round 3: conv1 rebuilt on the m97 staging pattern.
//  - A (weights) staged to LDS via global_load_lds(16B), triple-buffered,
//    one __syncthreads per K-step (batches the latency drain).
//  - M=64 per block (acc = 64 AGPR) -> launch_bounds(256,3) -> 3 blocks/CU.
//  - Grid 800 blocks: (tl 25 x kq 2 x mhalf 2, b 8). K-step = 32 ch; 144 steps.
//  - B spikes: bit-packed bytes, register-prefetched one step ahead.
//
// Workspace (peak ~69.6 MB), lifetime-aliased as round 2.
// ---------------------------------------------------------------------------

typedef _Float16 half8 __attribute__((ext_vector_type(8)));
typedef float f32x4 __attribute__((ext_vector_type(4)));
typedef unsigned int uint4v __attribute__((ext_vector_type(4)));

union AFrag { uint4v u4; unsigned int u[4]; half8 h; };

typedef const __attribute__((address_space(1))) unsigned int g_u32;
typedef __attribute__((address_space(3))) unsigned int l_u32;

__device__ inline void stage16(const void* g, void* l) {
  __builtin_amdgcn_global_load_lds((g_u32*)g, (l_u32*)l, 16, 0, 0);
}

__global__ __launch_bounds__(256) void k_linear(
    const float* __restrict__ z, const float* __restrict__ w,
    const float* __restrict__ bias, float* __restrict__ out) {
  int g = blockIdx.x * 256 + threadIdx.x;   // 65536 = (b, j)
  int b = g >> 13, j = g & 8191;
  float acc = bias[j];
  const float* zp = z + b * 100;
  for (int l = 0; l < 100; ++l) acc += zp[l] * w[l * 8192 + j];
  out[g] = acc;
}

// BN1 (stats over 512, eps 1e-5) + nearest upsample 2x -> I (8,128,16,16)
__global__ __launch_bounds__(256) void k_bn1_up(
    const float* __restrict__ lin, const float* __restrict__ g1,
    const float* __restrict__ be1, float* __restrict__ I) {
  int ch = blockIdx.x, tid = threadIdx.x;
  __shared__ float red[256];
  int n0 = tid, n1 = tid + 256;                       // n = b*64 + hw
  float v0 = lin[(n0 >> 6) * 8192 + ch * 64 + (n0 & 63)];
  float v1 = lin[(n1 >> 6) * 8192 + ch * 64 + (n1 & 63)];
  red[tid] = v0 + v1; __syncthreads();
  for (int s = 128; s > 0; s >>= 1) { if (tid < s) red[tid] += red[tid + s]; __syncthreads(); }
  float mean = red[0] * (1.0f / 512.0f);
  __syncthreads();
  float d0 = v0 - mean, d1 = v1 - mean;
  red[tid] = d0 * d0 + d1 * d1; __syncthreads();
  for (int s = 128; s > 0; s >>= 1) { if (tid < s) red[tid] += red[tid + s]; __syncthreads(); }
  float var = red[0] * (1.0f / 512.0f);
  float coef = g1[ch] / sqrtf(var + 1e-5f);
  float beta = be1[ch];
  float q0 = (v0 - mean) * coef + beta;
  float q1 = (v1 - mean) * coef + beta;
#pragma unroll
  for (int k = 0; k < 2; ++k) {
    int n = k ? n1 : n0; float q = k ? q1 : q0;
    int b = n >> 6, hw = n & 63, h = hw >> 3, w = hw & 7;
    float* o = I + (size_t)(b * 128 + ch) * 256 + (2 * h) * 16 + 2 * w;
    o[0] = q; o[1] = q; o[16] = q; o[17] = q;
  }
}

// LIF with bit-packed transposed spike output.
// spkTb[pos][col/8] bit (col&7), col = t*1024 + plane. Halo pre-zeroed.
__global__ __launch_bounds__(256) void k_lif(
    const float* __restrict__ I, unsigned char* __restrict__ spkTb) {
  int g = blockIdx.x * 256 + threadIdx.x;
  int px = g >> 10, plane = g & 1023;
  int lane = threadIdx.x & 63;
  float in = I[plane * 256 + px];
  int pos = ((px >> 4) + 1) * 18 + (px & 15) + 1;
  unsigned long long* wsrow =
      (unsigned long long*)(spkTb + (size_t)pos * 25600 + ((plane - lane) >> 3));
  float mem = 0.0f;
  for (int t = 0; t < 200; ++t) {
    float reset = (mem > 1.0f) ? 1.0f : 0.0f;
    mem = 0.95f * mem + in - reset;
    unsigned long long m = __ballot(mem > 1.0f);
    if (lane == 0) wsrow[t * 16] = m;   // t*128 bytes
  }
}

// One-time weight transform: w_c1 (128,25600,3,3) fp32 -> wT[tap][oc][c] f16
__global__ __launch_bounds__(256) void k_wtrans(
    const float* __restrict__ wc1, _Float16* __restrict__ wT) {
  size_t g = (size_t)blockIdx.x * 256 + threadIdx.x;  // oc*25600 + c
  int oc = (int)(g / 25600);
  int c  = (int)(g - (size_t)oc * 25600);
  const float* src = wc1 + g * 9;
#pragma unroll
  for (int tap = 0; tap < 9; ++tap)
    wT[(size_t)(tap * 128 + oc) * 25600 + c] = (_Float16)src[tap];
}

__device__ inline void expand8(unsigned int v, AFrag& f) {
  // bit j -> f16 element j (0x3C00 = 1.0h)
  f.u[0] = ((v & 1u) * 0x3C00u)        | (((v >> 1) & 1u) * 0x3C000000u);
  f.u[1] = (((v >> 2) & 1u) * 0x3C00u) | (((v >> 3) & 1u) * 0x3C000000u);
  f.u[2] = (((v >> 4) & 1u) * 0x3C00u) | (((v >> 5) & 1u) * 0x3C000000u);
  f.u[3] = (((v >> 6) & 1u) * 0x3C00u) | (((v >> 7) & 1u) * 0x3C000000u);
}

// conv1 implicit GEMM, LDS-staged A, triple-buffered, 1 barrier/step.
// Block = (part = tl*4 + kq*2 + mhalf, b). M=64 oc, N=256 px,
// K-chunk = 512 ch x 9 taps, step = 32 ch. Wave w: spatial rows 4w..4w+3.
// MFMA 16x16x32 f16: A[m=lane&15][k=quad*8+j], B[k][n=lane&15],
// D: col=lane&15, row=quad*4+reg. Partials atomicAdd into y1 (zero-init).
__global__ __launch_bounds__(256, 3) void k_conv1_mfma(
    const unsigned char* __restrict__ spkTb, const _Float16* __restrict__ wT,
    float* __restrict__ y1) {
  int part = blockIdx.x;            // 0..99
  int b    = blockIdx.y;            // 0..7
  int tl = part >> 2, kq = (part >> 1) & 1, mhalf = part & 1;
  int wave = threadIdx.x >> 6, lane = threadIdx.x & 63;
  int quad = lane >> 4, l16 = lane & 15;
  int T = b * 25 + tl;
  int cbase = tl * 1024 + kq * 512;            // A channel base (f16 elems)
  int colbyte = T * 128 + kq * 64 + quad;      // B column-byte base
  const int h0 = wave * 4;

  // A staging: wave w stages oc rows [mhalf*64 + w*16, +16), 32 ch = 1 KB.
  int rowA = mhalf * 64 + wave * 16 + (lane >> 2);
  size_t abase_lane = (size_t)rowA * 25600 + cbase + (lane & 3) * 8;

  __shared__ __align__(16) _Float16 Abuf[3][2048];   // [buf][64 rows][32 ch]
  _Float16* mydst0 = &Abuf[0][wave * 512];
  _Float16* mydst1 = &Abuf[1][wave * 512];
  _Float16* mydst2 = &Abuf[2][wave * 512];
  _Float16* dsts[3] = {mydst0, mydst1, mydst2};

  // B byte pointers per nt (spatial row), fixed; per-step offset added.
  const unsigned char* bptr[4];
#pragma unroll
  for (int nt = 0; nt < 4; ++nt)
    bptr[nt] = spkTb + (size_t)((h0 + nt) * 18 + l16) * 25600 + colbyte;

  f32x4 acc[4][4] = {};             // [mt][nt], 64 AGPRs

  // prologue: stage step 0 (tap=0, ks=0), load B step 0
  stage16(wT + abase_lane, mydst0);
  unsigned char bc[4], bn[4];
#pragma unroll
  for (int nt = 0; nt < 4; ++nt) bc[nt] = bptr[nt][0];
  __syncthreads();

  int cbuf = 0;
  for (int s = 0; s < 144; ++s) {
    int nb = cbuf + 1; if (nb == 3) nb = 0;
    int s1 = s + 1;
    if (s1 < 144) {
      int tap1 = s1 >> 4, ks1 = s1 & 15;
      int dh1 = tap1 / 3, dw1 = tap1 - dh1 * 3;
      stage16(wT + abase_lane + (size_t)tap1 * 3276800 + ks1 * 32, dsts[nb]);
      int boff1 = (dh1 * 18 + dw1) * 25600 + ks1 * 4;
#pragma unroll
      for (int nt = 0; nt < 4; ++nt) bn[nt] = bptr[nt][boff1];
    }
    // compute step s from Abuf[cbuf] and bc
    AFrag af[4];
#pragma unroll
    for (int mt = 0; mt < 4; ++mt)
      af[mt].u4 = *(const uint4v*)&Abuf[cbuf][(mt * 16 + l16) * 32 + quad * 8];
    AFrag bfr[4];
#pragma unroll
    for (int nt = 0; nt < 4; ++nt) expand8((unsigned int)bc[nt], bfr[nt]);
#pragma unroll
    for (int mt = 0; mt < 4; ++mt)
#pragma unroll
      for (int nt = 0; nt < 4; ++nt)
        acc[mt][nt] = __builtin_amdgcn_mfma_f32_16x16x32_f16(
            af[mt].h, bfr[nt].h, acc[mt][nt], 0, 0, 0);
#pragma unroll
    for (int nt = 0; nt < 4; ++nt) bc[nt] = bn[nt];
    cbuf = nb;
    __syncthreads();
  }

  float* ybase = y1 + (size_t)b * 128 * 256;
#pragma unroll
  for (int mt = 0; mt < 4; ++mt)
#pragma unroll
    for (int nt = 0; nt < 4; ++nt) {
      int h = h0 + nt;
#pragma unroll
      for (int r = 0; r < 4; ++r) {
        int oc = mhalf * 64 + mt * 16 + quad * 4 + r;
        atomicAdd(&ybase[(size_t)oc * 256 + h * 16 + l16], acc[mt][nt][r]);
      }
    }
}

// BN2 (eps 0.8, stats over 2048) + conv1 bias + leaky(0.2) + upsample2x
__global__ __launch_bounds__(256) void k_bn2_up(
    const float* __restrict__ y1, const float* __restrict__ bc1,
    const float* __restrict__ g2, const float* __restrict__ be2,
    float* __restrict__ x2p) {
  int ch = blockIdx.x, tid = threadIdx.x;
  __shared__ float red[256];
  float bias = bc1[ch];
  float v[8]; float s = 0.0f;
#pragma unroll
  for (int k = 0; k < 8; ++k) {
    int n = tid + k * 256;  // n = b*256 + px
    v[k] = y1[(size_t)((n >> 8) * 128 + ch) * 256 + (n & 255)] + bias;
    s += v[k];
  }
  red[tid] = s; __syncthreads();
  for (int st = 128; st > 0; st >>= 1) { if (tid < st) red[tid] += red[tid + st]; __syncthreads(); }
  float mean = red[0] * (1.0f / 2048.0f);
  __syncthreads();
  s = 0.0f;
#pragma unroll
  for (int k = 0; k < 8; ++k) { float d = v[k] - mean; s += d * d; }
  red[tid] = s; __syncthreads();
  for (int st = 128; st > 0; st >>= 1) { if (tid < st) red[tid] += red[tid + st]; __syncthreads(); }
  float var = red[0] * (1.0f / 2048.0f);
  float coef = g2[ch] / sqrtf(var + 0.8f);
  float beta = be2[ch];
#pragma unroll
  for (int k = 0; k < 8; ++k) {
    int n = tid + k * 256;
    int b = n >> 8, px = n & 255, h = px >> 4, w = px & 15;
    float q = (v[k] - mean) * coef + beta;
    q = (q >= 0.0f) ? q : 0.2f * q;
    float* o = x2p + (size_t)(b * 128 + ch) * 1156 + (2 * h + 1) * 34 + (2 * w + 1);
    o[0] = q; o[1] = q; o[34] = q; o[35] = q;
  }
}

// conv2: block=(octile 0..15, b), thread = 4 pixels x 4 oc
__global__ __launch_bounds__(256) void k_conv2(
    const float* __restrict__ x2p, const float* __restrict__ wc2,
    const float* __restrict__ bc2, float* __restrict__ y2) {
  int octile = blockIdx.x, b = blockIdx.y, tid = threadIdx.x;
  float acc[16];
#pragma unroll
  for (int i = 0; i < 16; ++i) acc[i] = 0.0f;
  const float* base = x2p + (size_t)(b * 128) * 1156;
  for (int ch = 0; ch < 128; ++ch) {
    const float* pl = base + (size_t)ch * 1156;
    float sv[4][9];
#pragma unroll
    for (int j = 0; j < 4; ++j) {
      int p = tid + j * 256, h = p >> 5, w = p & 31;
      const float* pp = pl + h * 34 + w;
      sv[j][0] = pp[0];  sv[j][1] = pp[1];  sv[j][2] = pp[2];
      sv[j][3] = pp[34]; sv[j][4] = pp[35]; sv[j][5] = pp[36];
      sv[j][6] = pp[68]; sv[j][7] = pp[69]; sv[j][8] = pp[70];
    }
#pragma unroll
    for (int ol = 0; ol < 4; ++ol) {
      const float* wp = wc2 + (size_t)((octile * 4 + ol) * 128 + ch) * 9;
#pragma unroll
      for (int j = 0; j < 4; ++j) {
        acc[ol * 4 + j] += sv[j][0] * wp[0] + sv[j][1] * wp[1] + sv[j][2] * wp[2]
                         + sv[j][3] * wp[3] + sv[j][4] * wp[4] + sv[j][5] * wp[5]
                         + sv[j][6] * wp[6] + sv[j][7] * wp[7] + sv[j][8] * wp[8];
      }
    }
  }
#pragma unroll
  for (int ol = 0; ol < 4; ++ol) {
    int oc = octile * 4 + ol;
    float bias = bc2[oc];
#pragma unroll
    for (int j = 0; j < 4; ++j)
      y2[(size_t)(b * 64 + oc) * 1024 + tid + j * 256] = acc[ol * 4 + j] + bias;
  }
}

// BN3 (eps 0.8, stats over 8192) + leaky -> padded y2n
__global__ __launch_bounds__(256) void k_bn3(
    const float* __restrict__ y2, const float* __restrict__ g3,
    const float* __restrict__ be3, float* __restrict__ y2n) {
  int ch = blockIdx.x, tid = threadIdx.x;
  __shared__ float red[256];
  float v[32]; float s = 0.0f;
#pragma unroll
  for (int k = 0; k < 32; ++k) {
    int n = tid + k * 256;  // n = b*1024 + px
    v[k] = y2[(size_t)((n >> 10) * 64 + ch) * 1024 + (n & 1023)];
    s += v[k];
  }
  red[tid] = s; __syncthreads();
  for (int st = 128; st > 0; st >>= 1) { if (tid < st) red[tid] += red[tid + st]; __syncthreads(); }
  float mean = red[0] * (1.0f / 8192.0f);
  __syncthreads();
  s = 0.0f;
#pragma unroll
  for (int k = 0; k < 32; ++k) { float d = v[k] - mean; s += d * d; }
  red[tid] = s; __syncthreads();
  for (int st = 128; st > 0; st >>= 1) { if (tid < st) red[tid] += red[tid + st]; __syncthreads(); }
  float var = red[0] * (1.0f / 8192.0f);
  float coef = g3[ch] / sqrtf(var + 0.8f);
  float beta = be3[ch];
#pragma unroll
  for (int k = 0; k < 32; ++k) {
    int n = tid + k * 256;
    int b = n >> 10, px = n & 1023, h = px >> 5, w = px & 31;
    float q = (v[k] - mean) * coef + beta;
    q = (q >= 0.0f) ? q : 0.2f * q;
    y2n[(size_t)(b * 64 + ch) * 1156 + (h + 1) * 34 + (w + 1)] = q;
  }
}

// conv3 (3 oc) + bias + tanh -> d_out (8,3,32,32)
__global__ __launch_bounds__(256) void k_conv3(
    const float* __restrict__ y2n, const float* __restrict__ wc3,
    const float* __restrict__ bc3, float* __restrict__ out) {
  int quarter = blockIdx.x & 3, b = blockIdx.x >> 2;
  int p = quarter * 256 + threadIdx.x, h = p >> 5, w = p & 31;
  float a0 = 0.0f, a1 = 0.0f, a2 = 0.0f;
  const float* base = y2n + (size_t)(b * 64) * 1156 + h * 34 + w;
  for (int ch = 0; ch < 64; ++ch) {
    const float* pp = base + (size_t)ch * 1156;
    float s0 = pp[0],  s1 = pp[1],  s2 = pp[2];
    float s3 = pp[34], s4 = pp[35], s5 = pp[36];
    float s6 = pp[68], s7 = pp[69], s8 = pp[70];
    const float* w0 = wc3 + (size_t)ch * 9;
    const float* w1 = wc3 + (size_t)(64 + ch) * 9;
    const float* w2 = wc3 + (size_t)(128 + ch) * 9;
    a0 += s0*w0[0]+s1*w0[1]+s2*w0[2]+s3*w0[3]+s4*w0[4]+s5*w0[5]+s6*w0[6]+s7*w0[7]+s8*w0[8];
    a1 += s0*w1[0]+s1*w1[1]+s2*w1[2]+s3*w1[3]+s4*w1[4]+s5*w1[5]+s6*w1[6]+s7*w1[7]+s8*w1[8];
    a2 += s0*w2[0]+s1*w2[1]+s2*w2[2]+s3*w2[3]+s4*w2[4]+s5*w2[5]+s6*w2[6]+s7*w2[7]+s8*w2[8];
  }
  out[(size_t)(b * 3 + 0) * 1024 + p] = tanhf(a0 + bc3[0]);
  out[(size_t)(b * 3 + 1) * 1024 + p] = tanhf(a1 + bc3[1]);
  out[(size_t)(b * 3 + 2) * 1024 + p] = tanhf(a2 + bc3[2]);
}

extern "C" void kernel_launch(void* const* d_in, const int* in_sizes, int n_in,
                              void* d_out, int out_size, void* d_ws, size_t ws_size,
                              hipStream_t stream) {
  const float* z    = (const float*)d_in[0];
  const float* w_l1 = (const float*)d_in[1];
  const float* b_l1 = (const float*)d_in[2];
  const float* g1   = (const float*)d_in[3];
  const float* be1  = (const float*)d_in[4];
  const float* w_c1 = (const float*)d_in[5];
  const float* b_c1 = (const float*)d_in[6];
  const float* g2   = (const float*)d_in[7];
  const float* be2  = (const float*)d_in[8];
  const float* w_c2 = (const float*)d_in[9];
  const float* b_c2 = (const float*)d_in[10];
  const float* g3   = (const float*)d_in[11];
  const float* be3  = (const float*)d_in[12];
  const float* w_c3 = (const float*)d_in[13];
  const float* b_c3 = (const float*)d_in[14];
  float* out = (float*)d_out;

  char* ws = (char*)d_ws;
  // phase A
  _Float16* wT = (_Float16*)ws;                             // 58,982,400 B
  unsigned char* spkTb = (unsigned char*)(ws + 58982400);   //  8,294,400 B
  float* lin = (float*)(ws + 67276800);                     //    262,144 B
  float* I   = (float*)(ws + 67538944);                     //  1,048,576 B
  float* y1  = (float*)(ws + 68587520);                     //  1,048,576 B
  // phase B (aliases wT region; written only after conv1 completes)
  float* x2p = (float*)ws;                                  //  4,734,976 B
  float* y2n = (float*)(ws + 4734976);                      //  2,367,488 B
  float* y2  = (float*)(ws + 7102464);                      //  2,097,152 B

  size_t spkTb_bytes = (size_t)324 * 25600;

  hipMemsetAsync(spkTb, 0, spkTb_bytes, stream);
  hipMemsetAsync(y1, 0, (size_t)262144 * 4, stream);

  k_wtrans <<<12800, 256, 0, stream>>>(w_c1, wT);
  k_linear <<<256, 256, 0, stream>>>(z, w_l1, b_l1, lin);
  k_bn1_up <<<128, 256, 0, stream>>>(lin, g1, be1, I);
  k_lif    <<<1024, 256, 0, stream>>>(I, spkTb);
  k_conv1_mfma<<<dim3(100, 8), 256, 0, stream>>>(spkTb, wT, y1);

  // phase B setup (must be after conv1: x2p/y2n alias the wT region)
  hipMemsetAsync(x2p, 0, (size_t)1183744 * 4, stream);
  hipMemsetAsync(y2n, 0, (size_t)591872 * 4, stream);

  k_bn2_up <<<128, 256, 0, stream>>>(y1, b_c1, g2, be2, x2p);
  k_conv2  <<<dim3(16, 8), 256, 0, stream>>>(x2p, w_c2, b_c2, y2);
  k_bn3    <<<64, 256, 0, stream>>>(y2, g3, be3, y2n);
  k_conv3  <<<32, 256, 0, stream>>>(y2n, w_c3, b_c3, out);
}

// Round 5
// 702.573 us; speedup vs baseline: 7.7910x; 1.0982x over previous
//
#include <hip/hip_runtime.h>
#include <math.h>

// ---------------------------------------------------------------------------
// SNN generator. Round 5:
//  - conv1: no LDS, no barriers. Waves partition M (32 oc each), block =
//    M128 x N256 (one batch), K = 512ch x 9 taps. Weights+spikes stream from
//    global; bit->f16 expand via multiply-spread + v_perm (~12 VALU/byte).
//  - k_wtrans: LDS-transposed (coalesced reads AND writes); was ~300us of
//    scattered 2B stores.
// Workspace (peak ~69.6 MB), lifetime-aliased as round 2.
// ---------------------------------------------------------------------------

typedef _Float16 half8 __attribute__((ext_vector_type(8)));
typedef float f32x4 __attribute__((ext_vector_type(4)));
typedef unsigned int uint4v __attribute__((ext_vector_type(4)));

union AFrag { uint4v u4; unsigned int u[4]; half8 h; };

__global__ __launch_bounds__(256) void k_linear(
    const float* __restrict__ z, const float* __restrict__ w,
    const float* __restrict__ bias, float* __restrict__ out) {
  int g = blockIdx.x * 256 + threadIdx.x;   // 65536 = (b, j)
  int b = g >> 13, j = g & 8191;
  float acc = bias[j];
  const float* zp = z + b * 100;
  for (int l = 0; l < 100; ++l) acc += zp[l] * w[l * 8192 + j];
  out[g] = acc;
}

// BN1 (stats over 512, eps 1e-5) + nearest upsample 2x -> I (8,128,16,16)
__global__ __launch_bounds__(256) void k_bn1_up(
    const float* __restrict__ lin, const float* __restrict__ g1,
    const float* __restrict__ be1, float* __restrict__ I) {
  int ch = blockIdx.x, tid = threadIdx.x;
  __shared__ float red[256];
  int n0 = tid, n1 = tid + 256;                       // n = b*64 + hw
  float v0 = lin[(n0 >> 6) * 8192 + ch * 64 + (n0 & 63)];
  float v1 = lin[(n1 >> 6) * 8192 + ch * 64 + (n1 & 63)];
  red[tid] = v0 + v1; __syncthreads();
  for (int s = 128; s > 0; s >>= 1) { if (tid < s) red[tid] += red[tid + s]; __syncthreads(); }
  float mean = red[0] * (1.0f / 512.0f);
  __syncthreads();
  float d0 = v0 - mean, d1 = v1 - mean;
  red[tid] = d0 * d0 + d1 * d1; __syncthreads();
  for (int s = 128; s > 0; s >>= 1) { if (tid < s) red[tid] += red[tid + s]; __syncthreads(); }
  float var = red[0] * (1.0f / 512.0f);
  float coef = g1[ch] / sqrtf(var + 1e-5f);
  float beta = be1[ch];
  float q0 = (v0 - mean) * coef + beta;
  float q1 = (v1 - mean) * coef + beta;
#pragma unroll
  for (int k = 0; k < 2; ++k) {
    int n = k ? n1 : n0; float q = k ? q1 : q0;
    int b = n >> 6, hw = n & 63, h = hw >> 3, w = hw & 7;
    float* o = I + (size_t)(b * 128 + ch) * 256 + (2 * h) * 16 + 2 * w;
    o[0] = q; o[1] = q; o[16] = q; o[17] = q;
  }
}

// LIF with bit-packed transposed spike output.
// spkTb[pos][col/8] bit (col&7), col = t*1024 + plane. Halo pre-zeroed.
__global__ __launch_bounds__(256) void k_lif(
    const float* __restrict__ I, unsigned char* __restrict__ spkTb) {
  int g = blockIdx.x * 256 + threadIdx.x;
  int px = g >> 10, plane = g & 1023;
  int lane = threadIdx.x & 63;
  float in = I[plane * 256 + px];
  int pos = ((px >> 4) + 1) * 18 + (px & 15) + 1;
  unsigned long long* wsrow =
      (unsigned long long*)(spkTb + (size_t)pos * 25600 + ((plane - lane) >> 3));
  float mem = 0.0f;
  for (int t = 0; t < 200; ++t) {
    float reset = (mem > 1.0f) ? 1.0f : 0.0f;
    mem = 0.95f * mem + in - reset;
    unsigned long long m = __ballot(mem > 1.0f);
    if (lane == 0) wsrow[t * 16] = m;   // t*128 bytes
  }
}

// Weight transform, LDS-transposed: w_c1 (128,25600,3,3) fp32 -> wT[tap][oc][c]
// Block = (oc 128 x cgroup 100): read 256 c x 9 taps contiguous fp32,
// write 9 contiguous 512B f16 runs.
__global__ __launch_bounds__(256) void k_wtrans(
    const float* __restrict__ wc1, _Float16* __restrict__ wT) {
  __shared__ float t[2304];
  int oc = blockIdx.x / 100, cg = blockIdx.x % 100;
  int c0 = cg * 256, tid = threadIdx.x;
  const float* src = wc1 + (size_t)oc * 230400 + (size_t)c0 * 9;
#pragma unroll
  for (int i = 0; i < 9; ++i) t[tid + i * 256] = src[tid + i * 256];
  __syncthreads();
#pragma unroll
  for (int tap = 0; tap < 9; ++tap)
    wT[(size_t)(tap * 128 + oc) * 25600 + c0 + tid] = (_Float16)t[tid * 9 + tap];
}

// bit->f16 expand: byte b -> 8 halfs {0,1.0h}, via multiply-spread + v_perm.
__device__ inline void expandp(unsigned int b, AFrag& f) {
  unsigned int lo = ((b & 0xFu) * 0x00204081u) & 0x01010101u;  // bits0-3 -> bytes
  unsigned int hi = ((b >> 4) * 0x00204081u) & 0x01010101u;    // bits4-7 -> bytes
  lo *= 0x3Cu; hi *= 0x3Cu;                                    // bytes 0x00 / 0x3C
  // D = [0, x.b0, 0, x.b1] => halfs (b0?1.0:0, b1?1.0:0); sel 4 picks from hi arg (=0)
  f.u[0] = __builtin_amdgcn_perm(0u, lo, 0x01040004u);
  f.u[1] = __builtin_amdgcn_perm(0u, lo, 0x03040204u);
  f.u[2] = __builtin_amdgcn_perm(0u, hi, 0x01040004u);
  f.u[3] = __builtin_amdgcn_perm(0u, hi, 0x03040204u);
}

// conv1 implicit GEMM, streaming, no LDS / no barriers.
// Block = (tl*2+kq, b). M=128 (wave w: oc 32w..32w+31), N=256 px, K=512ch x 9.
// bigstep = 128 ch: A = 8x16B loads, B = 16 nt x 16B dwordx4 (byte 'quad' of
// dword s = slice s's spike byte). MFMA 16x16x32 f16; D col=l16(px),
// row=quad*4+r (oc). Partials atomicAdd into zero-init y1.
__global__ __launch_bounds__(256, 2) void k_conv1_mfma(
    const unsigned char* __restrict__ spkTb, const _Float16* __restrict__ wT,
    float* __restrict__ y1) {
  int part = blockIdx.x;            // 0..49 = tl*2 + kq
  int b    = blockIdx.y;            // 0..7
  int tl = part >> 1, kq = part & 1;
  int wave = threadIdx.x >> 6, lane = threadIdx.x & 63;
  int quad = lane >> 4, l16 = lane & 15;
  int qs = quad * 8;
  int T = b * 25 + tl;
  int cbase = tl * 1024 + kq * 512;            // A channel base (f16 elems)

  // A: lane handles rows oc = wave*32 + mt*16 + l16
  const _Float16* a0 = wT + (size_t)(wave * 32 + l16) * 25600 + cbase + quad * 8;
  // B: dwordx4 base = pos*25600 + T*128 + kq*64 + s128*16, pos=(nt+dh)*18+l16+dw
  const unsigned char* b0 = spkTb + (size_t)l16 * 25600 + (size_t)T * 128 + kq * 64;

  f32x4 acc[2][16] = {};            // [mt][nt]

  for (int tap = 0; tap < 9; ++tap) {
    int dh = tap / 3, dw = tap - dh * 3;
    const _Float16* atap = a0 + (size_t)tap * 128 * 25600;
    const unsigned char* btap = b0 + (size_t)(dh * 18 + dw) * 25600;
    for (int s128 = 0; s128 < 4; ++s128) {
      AFrag af[2][4];
#pragma unroll
      for (int mt = 0; mt < 2; ++mt)
#pragma unroll
        for (int s = 0; s < 4; ++s)
          af[mt][s].u4 = *(const uint4v*)(atap + (size_t)mt * 16 * 25600 + s128 * 128 + s * 32);
#pragma unroll
      for (int ntc = 0; ntc < 4; ++ntc) {
        uint4v bx[4];
#pragma unroll
        for (int i = 0; i < 4; ++i)
          bx[i] = *(const uint4v*)(btap + (size_t)((ntc * 4 + i) * 18) * 25600 + s128 * 16);
#pragma unroll
        for (int i = 0; i < 4; ++i) {
          int nt = ntc * 4 + i;
#pragma unroll
          for (int s = 0; s < 4; ++s) {
            unsigned int byte = (bx[i][s] >> qs) & 0xFFu;
            AFrag bf; expandp(byte, bf);
            acc[0][nt] = __builtin_amdgcn_mfma_f32_16x16x32_f16(
                af[0][s].h, bf.h, acc[0][nt], 0, 0, 0);
            acc[1][nt] = __builtin_amdgcn_mfma_f32_16x16x32_f16(
                af[1][s].h, bf.h, acc[1][nt], 0, 0, 0);
          }
        }
      }
    }
  }

  float* ybase = y1 + (size_t)b * 128 * 256;
#pragma unroll
  for (int mt = 0; mt < 2; ++mt)
#pragma unroll
    for (int nt = 0; nt < 16; ++nt) {
#pragma unroll
      for (int r = 0; r < 4; ++r) {
        int oc = wave * 32 + mt * 16 + quad * 4 + r;
        atomicAdd(&ybase[(size_t)oc * 256 + nt * 16 + l16], acc[mt][nt][r]);
      }
    }
}

// BN2 (eps 0.8, stats over 2048) + conv1 bias + leaky(0.2) + upsample2x
__global__ __launch_bounds__(256) void k_bn2_up(
    const float* __restrict__ y1, const float* __restrict__ bc1,
    const float* __restrict__ g2, const float* __restrict__ be2,
    float* __restrict__ x2p) {
  int ch = blockIdx.x, tid = threadIdx.x;
  __shared__ float red[256];
  float bias = bc1[ch];
  float v[8]; float s = 0.0f;
#pragma unroll
  for (int k = 0; k < 8; ++k) {
    int n = tid + k * 256;  // n = b*256 + px
    v[k] = y1[(size_t)((n >> 8) * 128 + ch) * 256 + (n & 255)] + bias;
    s += v[k];
  }
  red[tid] = s; __syncthreads();
  for (int st = 128; st > 0; st >>= 1) { if (tid < st) red[tid] += red[tid + st]; __syncthreads(); }
  float mean = red[0] * (1.0f / 2048.0f);
  __syncthreads();
  s = 0.0f;
#pragma unroll
  for (int k = 0; k < 8; ++k) { float d = v[k] - mean; s += d * d; }
  red[tid] = s; __syncthreads();
  for (int st = 128; st > 0; st >>= 1) { if (tid < st) red[tid] += red[tid + st]; __syncthreads(); }
  float var = red[0] * (1.0f / 2048.0f);
  float coef = g2[ch] / sqrtf(var + 0.8f);
  float beta = be2[ch];
#pragma unroll
  for (int k = 0; k < 8; ++k) {
    int n = tid + k * 256;
    int b = n >> 8, px = n & 255, h = px >> 4, w = px & 15;
    float q = (v[k] - mean) * coef + beta;
    q = (q >= 0.0f) ? q : 0.2f * q;
    float* o = x2p + (size_t)(b * 128 + ch) * 1156 + (2 * h + 1) * 34 + (2 * w + 1);
    o[0] = q; o[1] = q; o[34] = q; o[35] = q;
  }
}

// conv2: block=(octile 0..15, b), thread = 4 pixels x 4 oc
__global__ __launch_bounds__(256) void k_conv2(
    const float* __restrict__ x2p, const float* __restrict__ wc2,
    const float* __restrict__ bc2, float* __restrict__ y2) {
  int octile = blockIdx.x, b = blockIdx.y, tid = threadIdx.x;
  float acc[16];
#pragma unroll
  for (int i = 0; i < 16; ++i) acc[i] = 0.0f;
  const float* base = x2p + (size_t)(b * 128) * 1156;
  for (int ch = 0; ch < 128; ++ch) {
    const float* pl = base + (size_t)ch * 1156;
    float sv[4][9];
#pragma unroll
    for (int j = 0; j < 4; ++j) {
      int p = tid + j * 256, h = p >> 5, w = p & 31;
      const float* pp = pl + h * 34 + w;
      sv[j][0] = pp[0];  sv[j][1] = pp[1];  sv[j][2] = pp[2];
      sv[j][3] = pp[34]; sv[j][4] = pp[35]; sv[j][5] = pp[36];
      sv[j][6] = pp[68]; sv[j][7] = pp[69]; sv[j][8] = pp[70];
    }
#pragma unroll
    for (int ol = 0; ol < 4; ++ol) {
      const float* wp = wc2 + (size_t)((octile * 4 + ol) * 128 + ch) * 9;
#pragma unroll
      for (int j = 0; j < 4; ++j) {
        acc[ol * 4 + j] += sv[j][0] * wp[0] + sv[j][1] * wp[1] + sv[j][2] * wp[2]
                         + sv[j][3] * wp[3] + sv[j][4] * wp[4] + sv[j][5] * wp[5]
                         + sv[j][6] * wp[6] + sv[j][7] * wp[7] + sv[j][8] * wp[8];
      }
    }
  }
#pragma unroll
  for (int ol = 0; ol < 4; ++ol) {
    int oc = octile * 4 + ol;
    float bias = bc2[oc];
#pragma unroll
    for (int j = 0; j < 4; ++j)
      y2[(size_t)(b * 64 + oc) * 1024 + tid + j * 256] = acc[ol * 4 + j] + bias;
  }
}

// BN3 (eps 0.8, stats over 8192) + leaky -> padded y2n
__global__ __launch_bounds__(256) void k_bn3(
    const float* __restrict__ y2, const float* __restrict__ g3,
    const float* __restrict__ be3, float* __restrict__ y2n) {
  int ch = blockIdx.x, tid = threadIdx.x;
  __shared__ float red[256];
  float v[32]; float s = 0.0f;
#pragma unroll
  for (int k = 0; k < 32; ++k) {
    int n = tid + k * 256;  // n = b*1024 + px
    v[k] = y2[(size_t)((n >> 10) * 64 + ch) * 1024 + (n & 1023)];
    s += v[k];
  }
  red[tid] = s; __syncthreads();
  for (int st = 128; st > 0; st >>= 1) { if (tid < st) red[tid] += red[tid + st]; __syncthreads(); }
  float mean = red[0] * (1.0f / 8192.0f);
  __syncthreads();
  s = 0.0f;
#pragma unroll
  for (int k = 0; k < 32; ++k) { float d = v[k] - mean; s += d * d; }
  red[tid] = s; __syncthreads();
  for (int st = 128; st > 0; st >>= 1) { if (tid < st) red[tid] += red[tid + st]; __syncthreads(); }
  float var = red[0] * (1.0f / 8192.0f);
  float coef = g3[ch] / sqrtf(var + 0.8f);
  float beta = be3[ch];
#pragma unroll
  for (int k = 0; k < 32; ++k) {
    int n = tid + k * 256;
    int b = n >> 10, px = n & 1023, h = px >> 5, w = px & 31;
    float q = (v[k] - mean) * coef + beta;
    q = (q >= 0.0f) ? q : 0.2f * q;
    y2n[(size_t)(b * 64 + ch) * 1156 + (h + 1) * 34 + (w + 1)] = q;
  }
}

// conv3 (3 oc) + bias + tanh -> d_out (8,3,32,32)
__global__ __launch_bounds__(256) void k_conv3(
    const float* __restrict__ y2n, const float* __restrict__ wc3,
    const float* __restrict__ bc3, float* __restrict__ out) {
  int quarter = blockIdx.x & 3, b = blockIdx.x >> 2;
  int p = quarter * 256 + threadIdx.x, h = p >> 5, w = p & 31;
  float a0 = 0.0f, a1 = 0.0f, a2 = 0.0f;
  const float* base = y2n + (size_t)(b * 64) * 1156 + h * 34 + w;
  for (int ch = 0; ch < 64; ++ch) {
    const float* pp = base + (size_t)ch * 1156;
    float s0 = pp[0],  s1 = pp[1],  s2 = pp[2];
    float s3 = pp[34], s4 = pp[35], s5 = pp[36];
    float s6 = pp[68], s7 = pp[69], s8 = pp[70];
    const float* w0 = wc3 + (size_t)ch * 9;
    const float* w1 = wc3 + (size_t)(64 + ch) * 9;
    const float* w2 = wc3 + (size_t)(128 + ch) * 9;
    a0 += s0*w0[0]+s1*w0[1]+s2*w0[2]+s3*w0[3]+s4*w0[4]+s5*w0[5]+s6*w0[6]+s7*w0[7]+s8*w0[8];
    a1 += s0*w1[0]+s1*w1[1]+s2*w1[2]+s3*w1[3]+s4*w1[4]+s5*w1[5]+s6*w1[6]+s7*w1[7]+s8*w1[8];
    a2 += s0*w2[0]+s1*w2[1]+s2*w2[2]+s3*w2[3]+s4*w2[4]+s5*w2[5]+s6*w2[6]+s7*w2[7]+s8*w2[8];
  }
  out[(size_t)(b * 3 + 0) * 1024 + p] = tanhf(a0 + bc3[0]);
  out[(size_t)(b * 3 + 1) * 1024 + p] = tanhf(a1 + bc3[1]);
  out[(size_t)(b * 3 + 2) * 1024 + p] = tanhf(a2 + bc3[2]);
}

extern "C" void kernel_launch(void* const* d_in, const int* in_sizes, int n_in,
                              void* d_out, int out_size, void* d_ws, size_t ws_size,
                              hipStream_t stream) {
  const float* z    = (const float*)d_in[0];
  const float* w_l1 = (const float*)d_in[1];
  const float* b_l1 = (const float*)d_in[2];
  const float* g1   = (const float*)d_in[3];
  const float* be1  = (const float*)d_in[4];
  const float* w_c1 = (const float*)d_in[5];
  const float* b_c1 = (const float*)d_in[6];
  const float* g2   = (const float*)d_in[7];
  const float* be2  = (const float*)d_in[8];
  const float* w_c2 = (const float*)d_in[9];
  const float* b_c2 = (const float*)d_in[10];
  const float* g3   = (const float*)d_in[11];
  const float* be3  = (const float*)d_in[12];
  const float* w_c3 = (const float*)d_in[13];
  const float* b_c3 = (const float*)d_in[14];
  float* out = (float*)d_out;

  char* ws = (char*)d_ws;
  // phase A
  _Float16* wT = (_Float16*)ws;                             // 58,982,400 B
  unsigned char* spkTb = (unsigned char*)(ws + 58982400);   //  8,294,400 B
  float* lin = (float*)(ws + 67276800);                     //    262,144 B
  float* I   = (float*)(ws + 67538944);                     //  1,048,576 B
  float* y1  = (float*)(ws + 68587520);                     //  1,048,576 B
  // phase B (aliases wT region; written only after conv1 completes)
  float* x2p = (float*)ws;                                  //  4,734,976 B
  float* y2n = (float*)(ws + 4734976);                      //  2,367,488 B
  float* y2  = (float*)(ws + 7102464);                      //  2,097,152 B

  size_t spkTb_bytes = (size_t)324 * 25600;

  hipMemsetAsync(spkTb, 0, spkTb_bytes, stream);
  hipMemsetAsync(y1, 0, (size_t)262144 * 4, stream);

  k_wtrans <<<12800, 256, 0, stream>>>(w_c1, wT);
  k_linear <<<256, 256, 0, stream>>>(z, w_l1, b_l1, lin);
  k_bn1_up <<<128, 256, 0, stream>>>(lin, g1, be1, I);
  k_lif    <<<1024, 256, 0, stream>>>(I, spkTb);
  k_conv1_mfma<<<dim3(50, 8), 256, 0, stream>>>(spkTb, wT, y1);

  // phase B setup (must be after conv1: x2p/y2n alias the wT region)
  hipMemsetAsync(x2p, 0, (size_t)1183744 * 4, stream);
  hipMemsetAsync(y2n, 0, (size_t)591872 * 4, stream);

  k_bn2_up <<<128, 256, 0, stream>>>(y1, b_c1, g2, be2, x2p);
  k_conv2  <<<dim3(16, 8), 256, 0, stream>>>(x2p, w_c2, b_c2, y2);
  k_bn3    <<<64, 256, 0, stream>>>(y2, g3, be3, y2n);
  k_conv3  <<<32, 256, 0, stream>>>(y2n, w_c3, b_c3, out);
}